// Round 13
// baseline (220.863 us; speedup 1.0000x reference)
//
#include <hip/hip_runtime.h>

#define HW 16384   // 128*128
#define NC 256     // C
#define NB 16      // B

typedef float floatx4 __attribute__((ext_vector_type(4)));

__device__ __forceinline__ float sum4(floatx4 v) { return (v.x + v.y) + (v.z + v.w); }
__device__ __forceinline__ floatx4 ntload(const floatx4* p) {
    return __builtin_nontemporal_load(p);
}

// ---------------------------------------------------------------------------
// MEASURED POLICY MATRIX (final):
//   pool: nt loads, 4096 blocks, 16-deep ILP  -> ~48us (5.6 TB/s HBM + L3)
//   apply: nt loads + caching stores, 2048 blocks x 2 contiguous planes,
//          8-load/4-store 16KB window -> 152.7us (best of 6 variants)
//   refuted levers: nt stores (+15..65us), caching loads (+40us), strided
//   direct-index shape (3x), coarser bursts (R12), deeper ILP w/o contiguity.
// R13: fused MLP + byte-exact R10 apply — disambiguates R12's flatline.
// ---------------------------------------------------------------------------

// ---------------------------------------------------------------------------
// Kernel 1: global average pool. 4096 blocks x 256 threads. Block bc reads
// plane bc of BOTH tensors with nt float4 loads, 16 loads in flight,
// independent partial accumulators, wave reduce, LDS combine. (frozen, ~48us)
// ---------------------------------------------------------------------------
__global__ __launch_bounds__(256, 4) void pool_kernel(const float* __restrict__ fft,
                                                      const float* __restrict__ multi,
                                                      float* __restrict__ pooled) {
    int bc = blockIdx.x;             // 0..4095 = b*256 + c
    int tid = threadIdx.x;
    int lane = tid & 63, wid = tid >> 6;
    const floatx4* fbase = (const floatx4*)fft + ((size_t)bc << 12) + tid;
    const floatx4* mbase = (const floatx4*)multi + ((size_t)bc << 12) + tid;

    float fs0 = 0.f, fs1 = 0.f, fs2 = 0.f, fs3 = 0.f;
    float fs4 = 0.f, fs5 = 0.f, fs6 = 0.f, fs7 = 0.f;
    float ms0 = 0.f, ms1 = 0.f, ms2 = 0.f, ms3 = 0.f;
    float ms4 = 0.f, ms5 = 0.f, ms6 = 0.f, ms7 = 0.f;

#pragma unroll
    for (int chunk = 0; chunk < 2; ++chunk) {
        const floatx4* pf = fbase + chunk * 2048;
        const floatx4* pm = mbase + chunk * 2048;
        floatx4 f0 = ntload(pf + 0),    f1 = ntload(pf + 256);
        floatx4 f2 = ntload(pf + 512),  f3 = ntload(pf + 768);
        floatx4 f4 = ntload(pf + 1024), f5 = ntload(pf + 1280);
        floatx4 f6 = ntload(pf + 1536), f7 = ntload(pf + 1792);
        floatx4 m0 = ntload(pm + 0),    m1 = ntload(pm + 256);
        floatx4 m2 = ntload(pm + 512),  m3 = ntload(pm + 768);
        floatx4 m4 = ntload(pm + 1024), m5 = ntload(pm + 1280);
        floatx4 m6 = ntload(pm + 1536), m7 = ntload(pm + 1792);
        fs0 += sum4(f0); fs1 += sum4(f1); fs2 += sum4(f2); fs3 += sum4(f3);
        fs4 += sum4(f4); fs5 += sum4(f5); fs6 += sum4(f6); fs7 += sum4(f7);
        ms0 += sum4(m0); ms1 += sum4(m1); ms2 += sum4(m2); ms3 += sum4(m3);
        ms4 += sum4(m4); ms5 += sum4(m5); ms6 += sum4(m6); ms7 += sum4(m7);
    }
    float fsum = ((fs0 + fs1) + (fs2 + fs3)) + ((fs4 + fs5) + (fs6 + fs7));
    float msum = ((ms0 + ms1) + (ms2 + ms3)) + ((ms4 + ms5) + (ms6 + ms7));

#pragma unroll
    for (int off = 32; off > 0; off >>= 1) {
        fsum += __shfl_xor(fsum, off, 64);
        msum += __shfl_xor(msum, off, 64);
    }

    __shared__ float ws[4][2];
    if (lane == 0) { ws[wid][0] = fsum; ws[wid][1] = msum; }
    __syncthreads();
    if (tid < 2) {
        float s = (ws[0][tid] + ws[1][tid]) + (ws[2][tid] + ws[3][tid]);
        int b = bc >> 8, c = bc & 255;
        pooled[b * 512 + tid * 256 + c] = s * (1.0f / HW);
    }
}

// ---------------------------------------------------------------------------
// Kernel 2 (FUSED MLP): one block per batch row b (16 blocks x 256 threads).
// Phase 1: h[r] = relu(dot(pooled[b], w1[r])), wave-per-output -> LDS.
// Phase 2: attn[b][c] = sigmoid(dot(h, w2[c])), thread-per-output x2,
//          contiguous per-thread w2-row reads (128KB, L2/L3-resident).
// ---------------------------------------------------------------------------
__global__ __launch_bounds__(256) void mlp_fused_kernel(const float* __restrict__ pooled,
                                                        const float* __restrict__ w1,
                                                        const float* __restrict__ w2,
                                                        float* __restrict__ attn) {
    __shared__ float h[64];
    int b = blockIdx.x;              // 0..15
    int tid = threadIdx.x;
    int lane = tid & 63, wid = tid >> 6;

    // ---- phase 1: 64 h-outputs, wave-per-output, 16 per wave ----
    const float4* pb = (const float4*)(pooled + b * 512) + (lane << 1);
    float4 pa = pb[0], pbv = pb[1];  // pooled slice for this lane (reused 16x)
#pragma unroll
    for (int i = 0; i < 16; ++i) {
        int r = (wid << 4) | i;      // wave wid handles rows 16w..16w+15
        const float4* w = (const float4*)(w1 + (size_t)r * 512) + (lane << 1);
        float4 wa = w[0], wb = w[1];
        float s = wa.x * pa.x + wa.y * pa.y + wa.z * pa.z + wa.w * pa.w
                + wb.x * pbv.x + wb.y * pbv.y + wb.z * pbv.z + wb.w * pbv.w;
#pragma unroll
        for (int off = 32; off > 0; off >>= 1) s += __shfl_xor(s, off, 64);
        if (lane == 0) h[r] = fmaxf(s, 0.f);
    }
    __syncthreads();

    // ---- phase 2: 512 attn-outputs, 2 per thread, contiguous w2 rows ----
#pragma unroll
    for (int half = 0; half < 2; ++half) {
        int c = (half << 8) | tid;   // 0..511
        const float4* w = (const float4*)(w2 + ((size_t)c << 6));
        const float4* hh = (const float4*)h;
        float s = 0.f;
#pragma unroll
        for (int k = 0; k < 16; ++k) {
            float4 wv = w[k];
            float4 hv = hh[k];
            s += wv.x * hv.x + wv.y * hv.y + wv.z * hv.z + wv.w * hv.w;
        }
        attn[(b << 9) | c] = 1.0f / (1.0f + __expf(-s));
    }
}

// ---------------------------------------------------------------------------
// Kernel 3: out = fw*fft + mw*multi. BYTE-EXACT R10 body (best measured:
// 152.7us). 2048 blocks x 256 threads; block g owns planes {2g,2g+1}
// contiguously; per 16KB window: 8 nt loads in flight, FMA, 4 caching
// stores. nt loads + caching stores = best policy cell.
// ---------------------------------------------------------------------------
__global__ __launch_bounds__(256) void apply_kernel(const float* __restrict__ fft,
                                                    const float* __restrict__ multi,
                                                    const float* __restrict__ attn,
                                                    float* __restrict__ out) {
    int g = blockIdx.x;              // 0..2047
    int tid = threadIdx.x;

#pragma unroll
    for (int pl = 0; pl < 2; ++pl) {
        int plane = (g << 1) | pl;   // b*256 + c
        int b = plane >> 8, c = plane & 255;
        float fw = attn[b * 512 + c];            // wave-uniform -> s_load
        float mw = attn[b * 512 + 256 + c];
        const floatx4* pf = (const floatx4*)fft + ((size_t)plane << 12) + tid;
        const floatx4* pm = (const floatx4*)multi + ((size_t)plane << 12) + tid;
        floatx4* po = (floatx4*)out + ((size_t)plane << 12) + tid;

#pragma unroll
        for (int it = 0; it < 4; ++it) {
            const floatx4* qf = pf + it * 1024;
            const floatx4* qm = pm + it * 1024;
            floatx4* qo = po + it * 1024;
            // 8 independent nt loads in flight, all within a 16 KB window
            floatx4 f0 = ntload(qf + 0),   f1 = ntload(qf + 256);
            floatx4 f2 = ntload(qf + 512), f3 = ntload(qf + 768);
            floatx4 m0 = ntload(qm + 0),   m1 = ntload(qm + 256);
            floatx4 m2 = ntload(qm + 512), m3 = ntload(qm + 768);
            floatx4 o0, o1, o2, o3;
            o0.x = fmaf(fw, f0.x, mw * m0.x); o0.y = fmaf(fw, f0.y, mw * m0.y);
            o0.z = fmaf(fw, f0.z, mw * m0.z); o0.w = fmaf(fw, f0.w, mw * m0.w);
            o1.x = fmaf(fw, f1.x, mw * m1.x); o1.y = fmaf(fw, f1.y, mw * m1.y);
            o1.z = fmaf(fw, f1.z, mw * m1.z); o1.w = fmaf(fw, f1.w, mw * m1.w);
            o2.x = fmaf(fw, f2.x, mw * m2.x); o2.y = fmaf(fw, f2.y, mw * m2.y);
            o2.z = fmaf(fw, f2.z, mw * m2.z); o2.w = fmaf(fw, f2.w, mw * m2.w);
            o3.x = fmaf(fw, f3.x, mw * m3.x); o3.y = fmaf(fw, f3.y, mw * m3.y);
            o3.z = fmaf(fw, f3.z, mw * m3.z); o3.w = fmaf(fw, f3.w, mw * m3.w);
            qo[0]   = o0;
            qo[256] = o1;
            qo[512] = o2;
            qo[768] = o3;
        }
    }
}

extern "C" void kernel_launch(void* const* d_in, const int* in_sizes, int n_in,
                              void* d_out, int out_size, void* d_ws, size_t ws_size,
                              hipStream_t stream) {
    const float* fft   = (const float*)d_in[0];
    const float* multi = (const float*)d_in[1];
    const float* w1    = (const float*)d_in[2];   // [64][512]
    const float* w2    = (const float*)d_in[3];   // [512][64]
    float* out = (float*)d_out;

    float* pooled = (float*)d_ws;                 // [16][512]
    float* attn   = pooled + NB * 512;            // [16][512]

    pool_kernel<<<4096, 256, 0, stream>>>(fft, multi, pooled);
    mlp_fused_kernel<<<NB, 256, 0, stream>>>(pooled, w1, w2, attn);
    apply_kernel<<<2048, 256, 0, stream>>>(fft, multi, attn, out);
}

// Round 14
// 210.966 us; speedup vs baseline: 1.0469x; 1.0469x over previous
//
#include <hip/hip_runtime.h>

#define HW 16384   // 128*128
#define NC 256     // C
#define NB 16      // B

typedef float floatx4 __attribute__((ext_vector_type(4)));

__device__ __forceinline__ float sum4(floatx4 v) { return (v.x + v.y) + (v.z + v.w); }
__device__ __forceinline__ floatx4 ntload(const floatx4* p) {
    return __builtin_nontemporal_load(p);
}

// ---------------------------------------------------------------------------
// FINAL CONFIG = byte-exact R10 (best measured: 216.0us).
//   pool:  nt loads, 4096 blocks, 16-deep ILP            ~48us
//   mlp1:  wave-per-output, 256 blocks                    \ ~8us both
//   mlp2:  wave-per-output, 2048 blocks                   /  (fused variant
//          was neutral-to-worse: 16-block kernel idles 240 CUs)
//   apply: nt loads + caching stores, 2048 blocks x 2 contiguous planes,
//          8-load/4-store 16KB window                     ~152.7us
// Steady-state HBM/replay = 804 MB == computed floor (L3 service at its
// 2x256MB/replay cap). Apply at 5.3 TB/s effective = 84% of copy ceiling.
// Refuted: nt stores (2x), caching loads post-nt-pool (2x), strided
// direct-index shape (3x), coarser bursts, deeper ILP, mlp fusion.
// ---------------------------------------------------------------------------

__global__ __launch_bounds__(256, 4) void pool_kernel(const float* __restrict__ fft,
                                                      const float* __restrict__ multi,
                                                      float* __restrict__ pooled) {
    int bc = blockIdx.x;             // 0..4095 = b*256 + c
    int tid = threadIdx.x;
    int lane = tid & 63, wid = tid >> 6;
    const floatx4* fbase = (const floatx4*)fft + ((size_t)bc << 12) + tid;
    const floatx4* mbase = (const floatx4*)multi + ((size_t)bc << 12) + tid;

    float fs0 = 0.f, fs1 = 0.f, fs2 = 0.f, fs3 = 0.f;
    float fs4 = 0.f, fs5 = 0.f, fs6 = 0.f, fs7 = 0.f;
    float ms0 = 0.f, ms1 = 0.f, ms2 = 0.f, ms3 = 0.f;
    float ms4 = 0.f, ms5 = 0.f, ms6 = 0.f, ms7 = 0.f;

#pragma unroll
    for (int chunk = 0; chunk < 2; ++chunk) {
        const floatx4* pf = fbase + chunk * 2048;
        const floatx4* pm = mbase + chunk * 2048;
        floatx4 f0 = ntload(pf + 0),    f1 = ntload(pf + 256);
        floatx4 f2 = ntload(pf + 512),  f3 = ntload(pf + 768);
        floatx4 f4 = ntload(pf + 1024), f5 = ntload(pf + 1280);
        floatx4 f6 = ntload(pf + 1536), f7 = ntload(pf + 1792);
        floatx4 m0 = ntload(pm + 0),    m1 = ntload(pm + 256);
        floatx4 m2 = ntload(pm + 512),  m3 = ntload(pm + 768);
        floatx4 m4 = ntload(pm + 1024), m5 = ntload(pm + 1280);
        floatx4 m6 = ntload(pm + 1536), m7 = ntload(pm + 1792);
        fs0 += sum4(f0); fs1 += sum4(f1); fs2 += sum4(f2); fs3 += sum4(f3);
        fs4 += sum4(f4); fs5 += sum4(f5); fs6 += sum4(f6); fs7 += sum4(f7);
        ms0 += sum4(m0); ms1 += sum4(m1); ms2 += sum4(m2); ms3 += sum4(m3);
        ms4 += sum4(m4); ms5 += sum4(m5); ms6 += sum4(m6); ms7 += sum4(m7);
    }
    float fsum = ((fs0 + fs1) + (fs2 + fs3)) + ((fs4 + fs5) + (fs6 + fs7));
    float msum = ((ms0 + ms1) + (ms2 + ms3)) + ((ms4 + ms5) + (ms6 + ms7));

#pragma unroll
    for (int off = 32; off > 0; off >>= 1) {
        fsum += __shfl_xor(fsum, off, 64);
        msum += __shfl_xor(msum, off, 64);
    }

    __shared__ float ws[4][2];
    if (lane == 0) { ws[wid][0] = fsum; ws[wid][1] = msum; }
    __syncthreads();
    if (tid < 2) {
        float s = (ws[0][tid] + ws[1][tid]) + (ws[2][tid] + ws[3][tid]);
        int b = bc >> 8, c = bc & 255;
        pooled[b * 512 + tid * 256 + c] = s * (1.0f / HW);
    }
}

// ---------------------------------------------------------------------------
// Kernel 2a: h[b][r] = relu(sum_c pooled[b][c] * w1[r][c]),  w1: [64][512]
// One wave per output (1024 outputs -> 256 blocks x 256 threads).
// ---------------------------------------------------------------------------
__global__ __launch_bounds__(256) void mlp1_kernel(const float* __restrict__ pooled,
                                                   const float* __restrict__ w1,
                                                   float* __restrict__ h) {
    int wid = (blockIdx.x << 2) | (threadIdx.x >> 6);   // 0..1023
    int lane = threadIdx.x & 63;
    int b = wid >> 6, r = wid & 63;
    const float4* w = (const float4*)(w1 + (size_t)r * 512) + (lane << 1);
    const float4* p = (const float4*)(pooled + b * 512) + (lane << 1);
    float4 wa = w[0], wb = w[1];
    float4 pa = p[0], pb = p[1];
    float s = wa.x * pa.x + wa.y * pa.y + wa.z * pa.z + wa.w * pa.w
            + wb.x * pb.x + wb.y * pb.y + wb.z * pb.z + wb.w * pb.w;
#pragma unroll
    for (int off = 32; off > 0; off >>= 1) s += __shfl_xor(s, off, 64);
    if (lane == 0) h[wid] = fmaxf(s, 0.f);
}

// ---------------------------------------------------------------------------
// Kernel 2b: attn[b][c] = sigmoid(sum_r h[b][r] * w2[c][r]),  w2: [512][64]
// One wave per output (8192 outputs -> 2048 blocks x 256 threads).
// ---------------------------------------------------------------------------
__global__ __launch_bounds__(256) void mlp2_kernel(const float* __restrict__ h,
                                                   const float* __restrict__ w2,
                                                   float* __restrict__ attn) {
    int wid = (blockIdx.x << 2) | (threadIdx.x >> 6);   // 0..8191
    int lane = threadIdx.x & 63;
    int b = wid >> 9, c = wid & 511;
    float s = h[(b << 6) | lane] * w2[((size_t)c << 6) | lane];
#pragma unroll
    for (int off = 32; off > 0; off >>= 1) s += __shfl_xor(s, off, 64);
    if (lane == 0) attn[(b << 9) | c] = 1.0f / (1.0f + __expf(-s));
}

// ---------------------------------------------------------------------------
// Kernel 3: out = fw*fft + mw*multi. R10 body (best measured: 152.7us).
// 2048 blocks x 256 threads; block g owns planes {2g,2g+1} contiguously;
// per 16KB window: 8 nt loads in flight, FMA, 4 caching stores.
// ---------------------------------------------------------------------------
__global__ __launch_bounds__(256) void apply_kernel(const float* __restrict__ fft,
                                                    const float* __restrict__ multi,
                                                    const float* __restrict__ attn,
                                                    float* __restrict__ out) {
    int g = blockIdx.x;              // 0..2047
    int tid = threadIdx.x;

#pragma unroll
    for (int pl = 0; pl < 2; ++pl) {
        int plane = (g << 1) | pl;   // b*256 + c
        int b = plane >> 8, c = plane & 255;
        float fw = attn[b * 512 + c];            // wave-uniform -> s_load
        float mw = attn[b * 512 + 256 + c];
        const floatx4* pf = (const floatx4*)fft + ((size_t)plane << 12) + tid;
        const floatx4* pm = (const floatx4*)multi + ((size_t)plane << 12) + tid;
        floatx4* po = (floatx4*)out + ((size_t)plane << 12) + tid;

#pragma unroll
        for (int it = 0; it < 4; ++it) {
            const floatx4* qf = pf + it * 1024;
            const floatx4* qm = pm + it * 1024;
            floatx4* qo = po + it * 1024;
            // 8 independent nt loads in flight, all within a 16 KB window
            floatx4 f0 = ntload(qf + 0),   f1 = ntload(qf + 256);
            floatx4 f2 = ntload(qf + 512), f3 = ntload(qf + 768);
            floatx4 m0 = ntload(qm + 0),   m1 = ntload(qm + 256);
            floatx4 m2 = ntload(qm + 512), m3 = ntload(qm + 768);
            floatx4 o0, o1, o2, o3;
            o0.x = fmaf(fw, f0.x, mw * m0.x); o0.y = fmaf(fw, f0.y, mw * m0.y);
            o0.z = fmaf(fw, f0.z, mw * m0.z); o0.w = fmaf(fw, f0.w, mw * m0.w);
            o1.x = fmaf(fw, f1.x, mw * m1.x); o1.y = fmaf(fw, f1.y, mw * m1.y);
            o1.z = fmaf(fw, f1.z, mw * m1.z); o1.w = fmaf(fw, f1.w, mw * m1.w);
            o2.x = fmaf(fw, f2.x, mw * m2.x); o2.y = fmaf(fw, f2.y, mw * m2.y);
            o2.z = fmaf(fw, f2.z, mw * m2.z); o2.w = fmaf(fw, f2.w, mw * m2.w);
            o3.x = fmaf(fw, f3.x, mw * m3.x); o3.y = fmaf(fw, f3.y, mw * m3.y);
            o3.z = fmaf(fw, f3.z, mw * m3.z); o3.w = fmaf(fw, f3.w, mw * m3.w);
            qo[0]   = o0;
            qo[256] = o1;
            qo[512] = o2;
            qo[768] = o3;
        }
    }
}

extern "C" void kernel_launch(void* const* d_in, const int* in_sizes, int n_in,
                              void* d_out, int out_size, void* d_ws, size_t ws_size,
                              hipStream_t stream) {
    const float* fft   = (const float*)d_in[0];
    const float* multi = (const float*)d_in[1];
    const float* w1    = (const float*)d_in[2];   // [64][512]
    const float* w2    = (const float*)d_in[3];   // [512][64]
    float* out = (float*)d_out;

    float* pooled = (float*)d_ws;                 // [16][512]
    float* h      = pooled + NB * 512;            // [16][64]
    float* attn   = h + NB * 64;                  // [16][512]

    pool_kernel<<<4096, 256, 0, stream>>>(fft, multi, pooled);
    mlp1_kernel<<<256, 256, 0, stream>>>(pooled, w1, h);
    mlp2_kernel<<<2048, 256, 0, stream>>>(h, w2, attn);
    apply_kernel<<<2048, 256, 0, stream>>>(fft, multi, attn, out);
}